// Round 10
// baseline (157.968 us; speedup 1.0000x reference)
//
#include <hip/hip_runtime.h>

typedef __attribute__((ext_vector_type(8))) short bf16x8;
typedef __attribute__((ext_vector_type(4))) short bf16x4;
typedef __attribute__((ext_vector_type(4))) float f32x4;

#if __has_builtin(__builtin_amdgcn_exp2f)
#define EXP2(x) __builtin_amdgcn_exp2f(x)
#else
#define EXP2(x) exp2f(x)
#endif

__device__ __forceinline__ unsigned short f2bf(float f) {
    union { float f; unsigned int u; } v; v.f = f;
    unsigned int r = v.u + 0x7fffu + ((v.u >> 16) & 1u);
    return (unsigned short)(r >> 16);
}

__device__ __forceinline__ float asf(unsigned int u) {
    union { unsigned int u; float f; } v; v.u = u; return v.f;
}

// sqrt( (1/sqrt(32)) * log2(e) ) — baked into BOTH xqT operands so QK^T
// emerges pre-multiplied by scale*log2e: exp2(raw score) == softmax numerator.
#define QK_PRESCALE 0.50500983f

// ---------------------------------------------------------------------------
// Kernel 1: grouped 1x1 conv, 1024 blocks.
// ---------------------------------------------------------------------------
__global__ __launch_bounds__(256) void conv_kernel(
    const float* __restrict__ points, const float* __restrict__ conv_w,
    const float* __restrict__ conv_b,
    unsigned short* __restrict__ xqT, unsigned short* __restrict__ xv)
{
    __shared__ float w[1024];
    const int h  = blockIdx.x >> 6;   // 16 heads
    const int nc = blockIdx.x & 63;   // 64 n-chunks of 64
    const int g  = h & 7;
    const int tid = threadIdx.x;
    const float* wg = conv_w + g * 1024;
    for (int k = tid; k < 1024; k += 256) w[k] = wg[k];
    __syncthreads();
    const int n  = nc * 64 + (tid & 63);
    const int ig = tid >> 6;          // wave id -> channels [ig*8, ig*8+8)
    const float* p = points + (size_t)h * 32 * 4096 + n;
    float pv[32];
#pragma unroll
    for (int j = 0; j < 32; ++j) pv[j] = p[(size_t)j * 4096];
    float out[8];
#pragma unroll
    for (int ii = 0; ii < 8; ++ii) {
        const int i = ig * 8 + ii;
        float acc = conv_b[g * 32 + i];
        const float4* w4 = (const float4*)(w + i * 32);   // ds_read_b128
#pragma unroll
        for (int j4 = 0; j4 < 8; ++j4) {
            float4 ww = w4[j4];
            acc += ww.x * pv[j4 * 4]     + ww.y * pv[j4 * 4 + 1]
                 + ww.z * pv[j4 * 4 + 2] + ww.w * pv[j4 * 4 + 3];
        }
        out[ii] = acc;
    }
    unsigned short tq[8];
#pragma unroll
    for (int ii = 0; ii < 8; ++ii) tq[ii] = f2bf(out[ii] * QK_PRESCALE);
    *(bf16x8*)(xqT + ((size_t)h * 4096 + n) * 32 + ig * 8) = *(bf16x8*)tq;
#pragma unroll
    for (int ii = 0; ii < 8; ++ii) {
        float x = out[ii];
        float e = x > 0.f ? x : (__expf(x) - 1.f);   // elu
        xv[((size_t)h * 32 + ig * 8 + ii) * 4096 + n] = f2bf(e);
    }
}

// ---------------------------------------------------------------------------
// Kernel 2: flash attention. R9 skeleton + (a) V LDS DOUBLE-BUFFER: single
// barrier per 128-key chunk (32 vs 64); store next-V into the idle buffer,
// compute from current. K frags stay direct-global double-buffered regs.
// (b) XCD swizzle: 1-D grid, h = (bid&7)*2 + ((bid>>3)&1) -> each XCD's
// blocks touch 2 heads (1MB K+V fits its 4MB L2). (c) epilogue writes
// per-(block,wave) GroupNorm partial sums to PRIVATE slots (no atomics).
// ---------------------------------------------------------------------------
#define VSTR 136   // 128 + 8 pad shorts
#define PSTR 72    // 64 + 8 pad shorts

#if __has_builtin(__builtin_amdgcn_cvt_pk_bf16_f32)
typedef __attribute__((ext_vector_type(2))) __bf16 bf16x2v;
__device__ __forceinline__ bf16x4 exp_pack(f32x4 sc, float& lsum) {
    float e0 = EXP2(sc[0]), e1 = EXP2(sc[1]);
    float e2 = EXP2(sc[2]), e3 = EXP2(sc[3]);
    lsum += (e0 + e1) + (e2 + e3);
    union { bf16x2v v[2]; bf16x4 s; } u;
    u.v[0] = __builtin_amdgcn_cvt_pk_bf16_f32(e0, e1);
    u.v[1] = __builtin_amdgcn_cvt_pk_bf16_f32(e2, e3);
    return u.s;
}
#else
__device__ __forceinline__ bf16x4 exp_pack(f32x4 sc, float& lsum) {
    union { float f; unsigned int u; } e0, e1, e2, e3;
    e0.f = EXP2(sc[0]); e1.f = EXP2(sc[1]); e2.f = EXP2(sc[2]); e3.f = EXP2(sc[3]);
    unsigned int t0 = e0.u & 0xffff0000u, t1 = e1.u & 0xffff0000u;
    unsigned int t2 = e2.u & 0xffff0000u, t3 = e3.u & 0xffff0000u;
    lsum += (asf(t0) + asf(t1)) + (asf(t2) + asf(t3));
    union { unsigned int d[2]; bf16x4 v; } pk;
    pk.d[0] = (t0 >> 16) | t1;
    pk.d[1] = (t2 >> 16) | t3;
    return pk.v;
}
#endif

// One 128-key chunk, SINGLE barrier. VCUR: computed-from buffer (stored last
// chunk). VNXT: idle buffer, gets V(C0+128) from regs va/vb. Then prefetch
// V(C0+256) -> va/vb and K(C0+128) -> KP, compute from VCUR/KU.
#define CHUNK(C0, KU, KP, VCUR, VNXT)                                          \
    {                                                                          \
        __syncthreads();                                                       \
        *(bf16x8*)((VNXT) + vi * VSTR + vn)      = va;                         \
        *(bf16x8*)((VNXT) + vi * VSTR + vn + 64) = vb;                         \
        const int pf1 = ((C0) + 128) & 4095;                                   \
        const int pf2 = ((C0) + 256) & 4095;                                   \
        va = *(const bf16x8*)(vbase + (size_t)vi * 4096 + pf2 + vn);           \
        vb = *(const bf16x8*)(vbase + (size_t)vi * 4096 + pf2 + vn + 64);      \
        _Pragma("unroll")                                                      \
        for (int s8 = 0; s8 < 8; ++s8)                                         \
            KP[s8] = *(const bf16x8*)(kfp + (size_t)(pf1 + s8 * 16) * 32);     \
        _Pragma("unroll")                                                      \
        for (int sub = 0; sub < 2; ++sub) {                                    \
            _Pragma("unroll")                                                  \
            for (int s = 0; s < 4; ++s) {                                      \
                f32x4 sc = __builtin_amdgcn_mfma_f32_16x16x32_bf16(            \
                    KU[sub * 4 + s], qfrag, (f32x4){0.f, 0.f, 0.f, 0.f},       \
                    0, 0, 0);                                                  \
                bf16x4 pk = exp_pack(sc, lsum);                                \
                *(bf16x4*)(pw + l15 * PSTR + s * 16 + quad * 4) = pk;          \
            }                                                                  \
            _Pragma("unroll")                                                  \
            for (int ng = 0; ng < 2; ++ng) {                                   \
                bf16x8 pfrag = *(const bf16x8*)(pw + l15 * PSTR + ng * 32 +    \
                                                quad * 8);                     \
                const int col = sub * 64 + ng * 32 + quad * 8;                 \
                bf16x8 v0 = *(const bf16x8*)((VCUR) + l15 * VSTR + col);       \
                bf16x8 v1 = *(const bf16x8*)((VCUR) + (16 + l15) * VSTR + col);\
                acc0 = __builtin_amdgcn_mfma_f32_16x16x32_bf16(v0, pfrag,      \
                                                               acc0, 0, 0, 0); \
                acc1 = __builtin_amdgcn_mfma_f32_16x16x32_bf16(v1, pfrag,      \
                                                               acc1, 0, 0, 0); \
            }                                                                  \
        }                                                                      \
    }

__global__ __launch_bounds__(256, 4) void attn_kernel(
    const unsigned short* __restrict__ xqT,
    const unsigned short* __restrict__ xv,
    const float* __restrict__ points,
    float* __restrict__ z, float* __restrict__ pstats)
{
    __shared__ unsigned short Vt0[32 * VSTR];   // V buffer A  8704 B
    __shared__ unsigned short Vt1[32 * VSTR];   // V buffer B  8704 B
    __shared__ unsigned short Pl[4][16 * PSTR]; // per-wave P  9216 B

    const int bid = blockIdx.x;                 // 1024 blocks, 1-D
    // XCD swizzle: blocks on XCD x (dispatch round-robin bid%8) get heads
    // {2x, 2x+1}: 1MB of K+V per XCD L2.
    const int h  = (bid & 7) * 2 + ((bid >> 3) & 1);
    const int qt = bid >> 4;
    const int b = h >> 3, g = h & 7;
    const int tid = threadIdx.x;
    const int wv = tid >> 6, lane = tid & 63;
    const int quad = lane >> 4, l15 = lane & 15;

    const int m = qt * 64 + wv * 16 + l15;      // this lane's query col

    const unsigned short* kbase = xqT + (size_t)h * 4096 * 32;
    const unsigned short* vbase = xv  + (size_t)h * 32 * 4096;

    // Q fragment (B-operand): col=l15, k=quad*8+j
    const bf16x8 qfrag = *(const bf16x8*)(kbase + (size_t)m * 32 + quad * 8);

    f32x4 acc0 = {0.f, 0.f, 0.f, 0.f};   // O rows i = 0..15
    f32x4 acc1 = {0.f, 0.f, 0.f, 0.f};   // O rows i = 16..31
    float lsum = 0.f;

    const int vi = tid >> 3, vn = (tid & 7) * 8;   // V staging: [i][n], 2 cols
    unsigned short* pw = &Pl[wv][0];

    // per-lane K-fragment base (A-operand K^T): row l15, cols quad*8..+8
    const unsigned short* kfp = kbase + (size_t)l15 * 32 + quad * 8;

    // Prologue: V(0) straight into buffer A; V(128) into regs; K(0) frags.
    {
        bf16x8 t0 = *(const bf16x8*)(vbase + (size_t)vi * 4096 + vn);
        bf16x8 t1 = *(const bf16x8*)(vbase + (size_t)vi * 4096 + vn + 64);
        *(bf16x8*)(Vt0 + vi * VSTR + vn)      = t0;
        *(bf16x8*)(Vt0 + vi * VSTR + vn + 64) = t1;
    }
    bf16x8 va = *(const bf16x8*)(vbase + (size_t)vi * 4096 + 128 + vn);
    bf16x8 vb = *(const bf16x8*)(vbase + (size_t)vi * 4096 + 128 + vn + 64);
    bf16x8 kA[8], kB[8];
#pragma unroll
    for (int s8 = 0; s8 < 8; ++s8)
        kA[s8] = *(const bf16x8*)(kfp + (size_t)(s8 * 16) * 32);

    for (int n0 = 0; n0 < 4096; n0 += 256) {
        CHUNK(n0,       kA, kB, Vt0, Vt1);
        CHUNK(n0 + 128, kB, kA, Vt1, Vt0);
    }

    // denominator: sum partial l over the 4 quads sharing column m
    lsum += __shfl_xor(lsum, 16, 64);
    lsum += __shfl_xor(lsum, 32, 64);
    const float inv = 1.f / lsum;

    const float* pb = points + (size_t)b * 256 * 4096;
    float* zb = z + (size_t)b * 256 * 4096;
    float* sb = pstats + ((size_t)bid * 4 + wv) * 64;   // private slot

#pragma unroll
    for (int half = 0; half < 2; ++half) {
        f32x4 a = half ? acc1 : acc0;
#pragma unroll
        for (int r = 0; r < 4; ++r) {
            const int i = half * 16 + quad * 4 + r;        // C/D row; gn group
            const size_t off = (size_t)(i * 8 + g) * 4096; // channel shuffle
            float zA = a[r] * inv + pb[off + m];
            zb[off + m] = zA;
            // GN partial sums over this wave's 16 query columns (no atomics)
            float s  = zA;
            float ss = zA * zA;
            s += __shfl_xor(s, 1, 64);  ss += __shfl_xor(ss, 1, 64);
            s += __shfl_xor(s, 2, 64);  ss += __shfl_xor(ss, 2, 64);
            s += __shfl_xor(s, 4, 64);  ss += __shfl_xor(ss, 4, 64);
            s += __shfl_xor(s, 8, 64);  ss += __shfl_xor(ss, 8, 64);
            if (l15 == 0) {
                sb[i * 2]     = s;
                sb[i * 2 + 1] = ss;
            }
        }
    }
}

// ---------------------------------------------------------------------------
// Kernel 3: combine GN partials. 64 blocks = (b, gn group i). Sums the 2048
// private slots whose head belongs to batch b; outputs mean & rstd.
// pstats layout: slot = bid*4 + wv; b(bid) = (bid>>2)&1.
// ---------------------------------------------------------------------------
__global__ __launch_bounds__(256) void gn_combine(const float* __restrict__ pstats,
                                                  float* __restrict__ stats)
{
    const int b = blockIdx.x >> 5;          // batch
    const int i = blockIdx.x & 31;          // gn group (== conv channel i)
    const int tid = threadIdx.x;
    float s = 0.f, ss = 0.f;
    for (int k = tid; k < 2048; k += 256) { // 512 bids x 4 waves
        const int wvk = k & 3, j = k >> 2;  // j in [0,512)
        const int bid = (j & 3) | (b << 2) | ((j >> 2) << 3);
        const float* p = pstats + ((size_t)bid * 4 + wvk) * 64 + i * 2;
        s += p[0]; ss += p[1];
    }
#pragma unroll
    for (int off = 32; off > 0; off >>= 1) {
        s  += __shfl_down(s, off, 64);
        ss += __shfl_down(ss, off, 64);
    }
    __shared__ float red[8];
    const int w = tid >> 6;
    if ((tid & 63) == 0) { red[w * 2] = s; red[w * 2 + 1] = ss; }
    __syncthreads();
    if (tid == 0) {
        s  = red[0] + red[2] + red[4] + red[6];
        ss = red[1] + red[3] + red[5] + red[7];
        float mean = s * (1.f / 32768.f);
        float var  = ss * (1.f / 32768.f) - mean * mean;
        stats[blockIdx.x * 2]     = mean;
        stats[blockIdx.x * 2 + 1] = rsqrtf(var + 1e-5f);
    }
}

// ---------------------------------------------------------------------------
// Kernel 4: GroupNorm apply, in place on d_out.
// ---------------------------------------------------------------------------
__global__ __launch_bounds__(256) void gn_apply(float* __restrict__ z,
                                                const float* __restrict__ stats,
                                                const float* __restrict__ gw,
                                                const float* __restrict__ gb)
{
    const int idx = blockIdx.x * 256 + threadIdx.x;  // float4 index
    float4* p = (float4*)z;
    float4 v = p[idx];
    const int chg = idx >> 10;       // global channel b*256+ch
    const int blk = chg >> 3;        // stats slot = b*32 + ch/8
    const int ch  = chg & 255;
    const float mean = stats[blk * 2], rstd = stats[blk * 2 + 1];
    const float w  = gw[ch] * rstd;
    const float bb = gb[ch] - mean * w;
    v.x = v.x * w + bb; v.y = v.y * w + bb;
    v.z = v.z * w + bb; v.w = v.w * w + bb;
    p[idx] = v;
}

extern "C" void kernel_launch(void* const* d_in, const int* in_sizes, int n_in,
                              void* d_out, int out_size, void* d_ws, size_t ws_size,
                              hipStream_t stream)
{
    const float* points = (const float*)d_in[0];
    const float* conv_w = (const float*)d_in[1];
    const float* conv_b = (const float*)d_in[2];
    const float* gn_w   = (const float*)d_in[3];
    const float* gn_b   = (const float*)d_in[4];
    float* out = (float*)d_out;
    char* ws = (char*)d_ws;
    unsigned short* xqT = (unsigned short*)ws;                              // 4 MB
    unsigned short* xv  = (unsigned short*)(ws + (size_t)4 * 1024 * 1024);  // 4 MB
    float* pstats = (float*)(ws + (size_t)8 * 1024 * 1024);                 // 1 MB
    float* stats  = (float*)(ws + (size_t)9 * 1024 * 1024);                 // 512 B

    conv_kernel<<<1024, 256, 0, stream>>>(points, conv_w, conv_b, xqT, xv);
    attn_kernel<<<1024, 256, 0, stream>>>(xqT, xv, points, out, pstats);
    gn_combine<<<64, 256, 0, stream>>>(pstats, stats);
    gn_apply<<<2048, 256, 0, stream>>>(out, stats, gn_w, gn_b);
}